// Round 5
// baseline (435.574 us; speedup 1.0000x reference)
//
#include <hip/hip_runtime.h>
#include <math.h>

#define NN 50000
#define EE 800000
#define DIN 256
#define NEG_SLOPE 0.01f

typedef __attribute__((ext_vector_type(8))) short bf16x8;
typedef __attribute__((ext_vector_type(8))) unsigned short u16x8;
typedef __attribute__((ext_vector_type(4))) float f32x4;

__device__ __forceinline__ unsigned short bf16_rne(float f) {
    unsigned int u = __float_as_uint(f);
    u += 0x7fffu + ((u >> 16) & 1u);
    return (unsigned short)(u >> 16);
}
__device__ __forceinline__ float bf16_tof(unsigned short h) {
    return __uint_as_float(((unsigned int)h) << 16);
}

// ---------------------------------------------------------------------------
// CSR build
// ---------------------------------------------------------------------------
__global__ __launch_bounds__(256) void hist_kernel(const int* __restrict__ dst,
                                                   int* __restrict__ cnt, int E) {
    int e = blockIdx.x * 256 + threadIdx.x;
    if (e < E) atomicAdd(&cnt[dst[e]], 1);
}

__global__ __launch_bounds__(1024) void scanA_kernel(int* __restrict__ cnt,
                                                     int* __restrict__ off,
                                                     int* __restrict__ aux, int Nn) {
    __shared__ int wsums[16];
    int tid = threadIdx.x, lane = tid & 63, w = tid >> 6;
    int i = blockIdx.x * 1024 + tid;
    int v = (i < Nn) ? cnt[i] : 0;
    if (i < Nn) cnt[i] = 0;
    int x = v;
#pragma unroll
    for (int d = 1; d < 64; d <<= 1) {
        int y = __shfl_up(x, d);
        if (lane >= d) x += y;
    }
    if (lane == 63) wsums[w] = x;
    __syncthreads();
    if (w == 0 && lane < 16) {
        int ws = wsums[lane];
#pragma unroll
        for (int d = 1; d < 16; d <<= 1) {
            int y = __shfl_up(ws, d);
            if (lane >= d) ws += y;
        }
        wsums[lane] = ws;
    }
    __syncthreads();
    int incl = x + (w > 0 ? wsums[w - 1] : 0);
    if (i < Nn) off[i + 1] = incl;
    if (tid == 1023) aux[blockIdx.x] = incl;
}

__global__ __launch_bounds__(1024) void scanC_kernel(const int* __restrict__ aux,
                                                     int* __restrict__ off, int Nn) {
    int b = blockIdx.x;
    int prefix = 0;
    for (int j = 0; j < b; j++) prefix += aux[j];
    int i = b * 1024 + threadIdx.x;
    if (i < Nn) off[i + 1] += prefix;
    if (i == 0 && b == 0) off[0] = 0;
}

__global__ __launch_bounds__(256) void scatter_kernel(const int* __restrict__ src,
                                                      const int* __restrict__ dst,
                                                      const int* __restrict__ off,
                                                      int* __restrict__ cnt,
                                                      int* __restrict__ esrc,
                                                      int* __restrict__ edst, int E) {
    int e = blockIdx.x * 256 + threadIdx.x;
    if (e >= E) return;
    int d = dst[e];
    int pos = atomicAdd(&cnt[d], 1) + off[d];
    esrc[pos] = src[e];
    edst[pos] = d;
}

// ---------------------------------------------------------------------------
// One-shot weight convert + transpose: W[H][D][64] -> Wt hi/lo [H*64][D]
// ---------------------------------------------------------------------------
__global__ __launch_bounds__(256) void conv_w_kernel(
    const float* __restrict__ W0, const float* __restrict__ W1,
    const float* __restrict__ Wf, unsigned short* __restrict__ w0h,
    unsigned short* __restrict__ w0l, unsigned short* __restrict__ w1h,
    unsigned short* __restrict__ w1l, unsigned short* __restrict__ wfh,
    unsigned short* __restrict__ wfl) {
    int t = blockIdx.x * 256 + threadIdx.x;
    const float* W;
    unsigned short *oh, *ol;
    int D, u;
    if (t < 32768) { W = W0; oh = w0h; ol = w0l; D = 256; u = t; }
    else if (t < 49152) { W = W1; oh = w1h; ol = w1l; D = 128; u = t - 32768; }
    else if (t < 57344) { W = Wf; oh = wfh; ol = wfl; D = 128; u = t - 49152; }
    else return;
    int d = u & (D - 1);
    int n = u / D;
    float v = W[((size_t)(n >> 6) * D + d) * 64 + (n & 63)];
    unsigned short hi = bf16_rne(v);
    unsigned short lo = bf16_rne(v - bf16_tof(hi));
    oh[(size_t)n * D + d] = hi;
    ol[(size_t)n * D + d] = lo;
}

// ---------------------------------------------------------------------------
// MFMA bf16x3 GEMM + fused attention dots (unchanged from R4 structure)
// ---------------------------------------------------------------------------
#define LDK 40

template <int NCOL, bool AFP32>
__global__ __launch_bounds__(256) void gemm_attn(
    const float* __restrict__ Xf, const unsigned short* __restrict__ Xhi,
    const unsigned short* __restrict__ Xlo, const unsigned short* __restrict__ Wthi,
    const unsigned short* __restrict__ Wtlo, const float* __restrict__ bias,
    const float* __restrict__ al, const float* __restrict__ bl,
    const float* __restrict__ ar, const float* __restrict__ br,
    float* __restrict__ FT, float* __restrict__ A1, float* __restrict__ A2,
    int Nn, int D) {
    const int H = NCOL / 64;
    const int NC16 = NCOL / 16;
    __shared__ __align__(16) unsigned short Ahi_s[64 * LDK];
    __shared__ __align__(16) unsigned short Alo_s[64 * LDK];
    __shared__ __align__(16) unsigned short Bhi_s[NCOL * LDK];
    __shared__ __align__(16) unsigned short Blo_s[NCOL * LDK];

    int tid = threadIdx.x;
    int wv = tid >> 6, l = tid & 63, lm = l & 15, quad = l >> 4;
    int m0 = blockIdx.x * 64;

    f32x4 acc[NC16];
#pragma unroll
    for (int c = 0; c < NC16; c++) acc[c] = (f32x4){0.f, 0.f, 0.f, 0.f};

    for (int d0 = 0; d0 < D; d0 += 32) {
        if (AFP32) {
#pragma unroll
            for (int i = 0; i < 2; i++) {
                int u = tid + i * 256;
                int row = u >> 3, c4 = u & 7;
                float4 v = make_float4(0.f, 0.f, 0.f, 0.f);
                if (m0 + row < Nn)
                    v = *(const float4*)&Xf[(size_t)(m0 + row) * D + d0 + c4 * 4];
                float f[4] = {v.x, v.y, v.z, v.w};
                unsigned short hi[4], lo[4];
#pragma unroll
                for (int j = 0; j < 4; j++) {
                    hi[j] = bf16_rne(f[j]);
                    lo[j] = bf16_rne(f[j] - bf16_tof(hi[j]));
                }
                *(ushort4*)&Ahi_s[row * LDK + c4 * 4] = make_ushort4(hi[0], hi[1], hi[2], hi[3]);
                *(ushort4*)&Alo_s[row * LDK + c4 * 4] = make_ushort4(lo[0], lo[1], lo[2], lo[3]);
            }
        } else {
            int row = tid >> 2, q = tid & 3;
            u16x8 vh = (u16x8)0, vl = (u16x8)0;
            if (m0 + row < Nn) {
                vh = *(const u16x8*)&Xhi[(size_t)(m0 + row) * D + d0 + q * 8];
                vl = *(const u16x8*)&Xlo[(size_t)(m0 + row) * D + d0 + q * 8];
            }
            *(u16x8*)&Ahi_s[row * LDK + q * 8] = vh;
            *(u16x8*)&Alo_s[row * LDK + q * 8] = vl;
        }
#pragma unroll
        for (int i = 0; i < NCOL / 64; i++) {
            int u = tid + i * 256;
            int n = u >> 2, q = u & 3;
            *(u16x8*)&Bhi_s[n * LDK + q * 8] =
                *(const u16x8*)&Wthi[(size_t)n * D + d0 + q * 8];
            *(u16x8*)&Blo_s[n * LDK + q * 8] =
                *(const u16x8*)&Wtlo[(size_t)n * D + d0 + q * 8];
        }
        __syncthreads();

        int arow = wv * 16 + lm;
        bf16x8 ah = *(const bf16x8*)&Ahi_s[arow * LDK + quad * 8];
        bf16x8 alo = *(const bf16x8*)&Alo_s[arow * LDK + quad * 8];
#pragma unroll
        for (int c = 0; c < NC16; c++) {
            bf16x8 bh = *(const bf16x8*)&Bhi_s[(c * 16 + lm) * LDK + quad * 8];
            bf16x8 blo = *(const bf16x8*)&Blo_s[(c * 16 + lm) * LDK + quad * 8];
            acc[c] = __builtin_amdgcn_mfma_f32_16x16x32_bf16(ah, bh, acc[c], 0, 0, 0);
            acc[c] = __builtin_amdgcn_mfma_f32_16x16x32_bf16(ah, blo, acc[c], 0, 0, 0);
            acc[c] = __builtin_amdgcn_mfma_f32_16x16x32_bf16(alo, bh, acc[c], 0, 0, 0);
        }
        __syncthreads();
    }

    float bj[NC16], alj[NC16], arj[NC16];
#pragma unroll
    for (int c = 0; c < NC16; c++) {
        bj[c] = bias[c * 16 + lm];
        alj[c] = al[c * 16 + lm];
        arj[c] = ar[c * 16 + lm];
    }
#pragma unroll
    for (int reg = 0; reg < 4; reg++) {
        int row = m0 + wv * 16 + quad * 4 + reg;
        bool ok = row < Nn;
        float s1[H], s2[H];
#pragma unroll
        for (int h = 0; h < H; h++) { s1[h] = 0.f; s2[h] = 0.f; }
#pragma unroll
        for (int c = 0; c < NC16; c++) {
            float o = acc[c][reg] + bj[c];
            int h = c >> 2;
            s1[h] += o * alj[c];
            s2[h] += o * arj[c];
            if (ok) FT[(size_t)row * NCOL + c * 16 + lm] = o;
        }
#pragma unroll
        for (int h = 0; h < H; h++) {
#pragma unroll
            for (int d = 1; d < 16; d <<= 1) {
                s1[h] += __shfl_xor(s1[h], d);
                s2[h] += __shfl_xor(s2[h], d);
            }
        }
        if (ok && lm == 0) {
#pragma unroll
            for (int h = 0; h < H; h++) {
                A1[(size_t)row * H + h] = s1[h] + bl[h];
                A2[(size_t)row * H + h] = s2[h] + br[h];
            }
        }
    }
}

// ---------------------------------------------------------------------------
// Phase A: per-CSR-slot edge scores w = exp(leaky_relu(a1[dst] + a2[src])).
// No max subtraction: scores are O(+-10), exp is safe in fp32 and alpha is
// mathematically identical to the reference's exp(s-m)/sum(exp(s-m)).
// ---------------------------------------------------------------------------
template <int H>
__global__ __launch_bounds__(256) void score_kernel(
    const int* __restrict__ esrc, const int* __restrict__ edst,
    const float* __restrict__ a1, const float* __restrict__ a2,
    float* __restrict__ w, int E) {
    int i = blockIdx.x * 256 + threadIdx.x;
    if (i >= E) return;
    int s = esrc[i], d = edst[i];
    if (H == 2) {
        float2 x1 = *(const float2*)&a1[(size_t)d * 2];
        float2 x2 = *(const float2*)&a2[(size_t)s * 2];
        float t0 = x1.x + x2.x;
        float t1 = x1.y + x2.y;
        t0 = t0 > 0.f ? t0 : NEG_SLOPE * t0;
        t1 = t1 > 0.f ? t1 : NEG_SLOPE * t1;
        *(float2*)&w[(size_t)i * 2] = make_float2(__expf(t0), __expf(t1));
    } else {
        float t = a1[d] + a2[s];
        t = t > 0.f ? t : NEG_SLOPE * t;
        w[i] = __expf(t);
    }
}

// ---------------------------------------------------------------------------
// Phase B: pure gather + FMA aggregation, one wave per dst node.
// H=2: lane owns ft elems 2*lane, 2*lane+1 (head = lane>>5); bf16 hi/lo out.
// ---------------------------------------------------------------------------
__global__ __launch_bounds__(256) void agg2_kernel(
    const float* __restrict__ ft, const float* __restrict__ w2,
    const int* __restrict__ off, const int* __restrict__ esrc,
    unsigned short* __restrict__ ohi, unsigned short* __restrict__ olo, int Nn) {
    __shared__ __align__(16) float ws[4][128];  // [wave][j*2 + h]
    __shared__ __align__(16) int sjs[4][64];
    int wv = threadIdx.x >> 6, lane = threadIdx.x & 63;
    int n = blockIdx.x * 4 + wv;
    if (n >= Nn) return;
    int o0 = off[n], deg = off[n + 1] - o0;
    int hs = lane >> 5, cl2 = lane * 2;
    if (deg == 0) {
        *(ushort2*)&ohi[(size_t)n * 128 + cl2] = make_ushort2(0, 0);
        *(ushort2*)&olo[(size_t)n * 128 + cl2] = make_ushort2(0, 0);
        return;
    }
    float ax = 0.f, ay = 0.f;
    float ds0 = 0.f, ds1 = 0.f;
    for (int e0 = 0; e0 < deg; e0 += 64) {
        int nE = min(64, deg - e0);
        float2 wl = make_float2(0.f, 0.f);
        int sj = 0;
        if (lane < nE) {
            wl = *(const float2*)&w2[(size_t)(o0 + e0 + lane) * 2];
            sj = esrc[o0 + e0 + lane];
        }
        ds0 += wl.x;
        ds1 += wl.y;
        *(float2*)&ws[wv][lane * 2] = wl;
        sjs[wv][lane] = sj;
        // wave-synchronous: DS ops in a wave execute in order, no barrier.
        int j = 0;
        for (; j + 8 <= nE; j += 8) {
            float wb[8];
            int sb[8];
#pragma unroll
            for (int u = 0; u < 8; u++) {
                wb[u] = ws[wv][(j + u) * 2 + hs];
                sb[u] = sjs[wv][j + u];
            }
            float2 f[8];
#pragma unroll
            for (int u = 0; u < 8; u++)
                f[u] = *(const float2*)&ft[(size_t)sb[u] * 128 + cl2];
#pragma unroll
            for (int u = 0; u < 8; u++) {
                ax += wb[u] * f[u].x;
                ay += wb[u] * f[u].y;
            }
        }
        for (; j < nE; j++) {
            float w = ws[wv][j * 2 + hs];
            int s0 = sjs[wv][j];
            float2 f = *(const float2*)&ft[(size_t)s0 * 128 + cl2];
            ax += w * f.x;
            ay += w * f.y;
        }
    }
#pragma unroll
    for (int d = 1; d < 64; d <<= 1) {
        ds0 += __shfl_xor(ds0, d);
        ds1 += __shfl_xor(ds1, d);
    }
    float rd = 1.f / (hs ? ds1 : ds0);
    float rx = ax * rd, ry = ay * rd;
    rx = rx > 0.f ? rx : expm1f(rx);
    ry = ry > 0.f ? ry : expm1f(ry);
    unsigned short hx = bf16_rne(rx), hy = bf16_rne(ry);
    unsigned short lx = bf16_rne(rx - bf16_tof(hx)), ly = bf16_rne(ry - bf16_tof(hy));
    *(ushort2*)&ohi[(size_t)n * 128 + cl2] = make_ushort2(hx, hy);
    *(ushort2*)&olo[(size_t)n * 128 + cl2] = make_ushort2(lx, ly);
}

// H=1: lane owns ft elem `lane`; fp32 output (d_out).
__global__ __launch_bounds__(256) void agg1_kernel(
    const float* __restrict__ ft, const float* __restrict__ w1,
    const int* __restrict__ off, const int* __restrict__ esrc,
    float* __restrict__ out, int Nn) {
    __shared__ __align__(16) float ws[4][64];
    __shared__ __align__(16) int sjs[4][64];
    int wv = threadIdx.x >> 6, lane = threadIdx.x & 63;
    int n = blockIdx.x * 4 + wv;
    if (n >= Nn) return;
    int o0 = off[n], deg = off[n + 1] - o0;
    if (deg == 0) {
        out[(size_t)n * 64 + lane] = 0.f;
        return;
    }
    float acc = 0.f, dsum = 0.f;
    for (int e0 = 0; e0 < deg; e0 += 64) {
        int nE = min(64, deg - e0);
        float wl = 0.f;
        int sj = 0;
        if (lane < nE) {
            wl = w1[o0 + e0 + lane];
            sj = esrc[o0 + e0 + lane];
        }
        dsum += wl;
        ws[wv][lane] = wl;
        sjs[wv][lane] = sj;
        int j = 0;
        for (; j + 8 <= nE; j += 8) {
            float wb[8];
            int sb[8];
#pragma unroll
            for (int u = 0; u < 8; u++) {
                wb[u] = ws[wv][j + u];
                sb[u] = sjs[wv][j + u];
            }
            float f[8];
#pragma unroll
            for (int u = 0; u < 8; u++) f[u] = ft[(size_t)sb[u] * 64 + lane];
#pragma unroll
            for (int u = 0; u < 8; u++) acc += wb[u] * f[u];
        }
        for (; j < nE; j++) acc += ws[wv][j] * ft[(size_t)sjs[wv][j] * 64 + lane];
    }
#pragma unroll
    for (int d = 1; d < 64; d <<= 1) dsum += __shfl_xor(dsum, d);
    float r = acc / dsum;
    out[(size_t)n * 64 + lane] = r > 0.f ? r : expm1f(r);
}

// ---------------------------------------------------------------------------
// launch
// ---------------------------------------------------------------------------
extern "C" void kernel_launch(void* const* d_in, const int* in_sizes, int n_in,
                              void* d_out, int out_size, void* d_ws, size_t ws_size,
                              hipStream_t stream) {
    const float* features = (const float*)d_in[0];
    const int* src = (const int*)d_in[1];
    const int* dst = (const int*)d_in[2];
    const float* W0 = (const float*)d_in[3];
    const float* b0 = (const float*)d_in[4];
    const float* al0 = (const float*)d_in[5];
    const float* bl0 = (const float*)d_in[6];
    const float* ar0 = (const float*)d_in[7];
    const float* br0 = (const float*)d_in[8];
    const float* W1 = (const float*)d_in[9];
    const float* b1 = (const float*)d_in[10];
    const float* al1 = (const float*)d_in[11];
    const float* bl1 = (const float*)d_in[12];
    const float* ar1 = (const float*)d_in[13];
    const float* br1 = (const float*)d_in[14];
    const float* Wf = (const float*)d_in[15];
    const float* bf = (const float*)d_in[16];
    const float* alf = (const float*)d_in[17];
    const float* blf = (const float*)d_in[18];
    const float* arf = (const float*)d_in[19];
    const float* brf = (const float*)d_in[20];

    char* p = (char*)d_ws;
    auto carve = [&](size_t bytes) {
        void* q = (void*)p;
        p += (bytes + 255) & ~(size_t)255;
        return q;
    };
    float* ft = (float*)carve((size_t)NN * 128 * 4);
    unsigned short* Xhi = (unsigned short*)carve((size_t)NN * 128 * 2);
    unsigned short* Xlo = (unsigned short*)carve((size_t)NN * 128 * 2);
    float* a1 = (float*)carve((size_t)NN * 2 * 4);
    float* a2 = (float*)carve((size_t)NN * 2 * 4);
    int* off = (int*)carve((size_t)(NN + 1) * 4);
    int* cnt = (int*)carve((size_t)NN * 4);
    int* esrc = (int*)carve((size_t)EE * 4);
    int* edst = (int*)carve((size_t)EE * 4);
    float* wbuf = (float*)carve((size_t)EE * 2 * 4);
    int* aux = (int*)carve(64 * 4);
    unsigned short* w0h = (unsigned short*)carve(32768 * 2);
    unsigned short* w0l = (unsigned short*)carve(32768 * 2);
    unsigned short* w1h = (unsigned short*)carve(16384 * 2);
    unsigned short* w1l = (unsigned short*)carve(16384 * 2);
    unsigned short* wfh = (unsigned short*)carve(8192 * 2);
    unsigned short* wfl = (unsigned short*)carve(8192 * 2);

    const int NB_SCAN = (NN + 1023) / 1024;
    const int GE = (EE + 255) / 256;

    // ---- CSR build + weight convert ----
    hipMemsetAsync(cnt, 0, (size_t)NN * 4, stream);
    hist_kernel<<<GE, 256, 0, stream>>>(dst, cnt, EE);
    scanA_kernel<<<NB_SCAN, 1024, 0, stream>>>(cnt, off, aux, NN);
    scanC_kernel<<<NB_SCAN, 1024, 0, stream>>>(aux, off, NN);
    scatter_kernel<<<GE, 256, 0, stream>>>(src, dst, off, cnt, esrc, edst, EE);
    conv_w_kernel<<<(57344 + 255) / 256, 256, 0, stream>>>(W0, W1, Wf, w0h, w0l, w1h,
                                                           w1l, wfh, wfl);

    const int gx = (NN + 63) / 64;
    const int gn = (NN + 3) / 4;

    // ---- layer 0: D=256, H=2 (fp32 A) ----
    gemm_attn<128, true><<<gx, 256, 0, stream>>>(features, nullptr, nullptr, w0h, w0l,
                                                 b0, al0, bl0, ar0, br0, ft, a1, a2,
                                                 NN, DIN);
    score_kernel<2><<<GE, 256, 0, stream>>>(esrc, edst, a1, a2, wbuf, EE);
    agg2_kernel<<<gn, 256, 0, stream>>>(ft, wbuf, off, esrc, Xhi, Xlo, NN);

    // ---- layer 1: D=128, H=2 (bf16 A) ----
    gemm_attn<128, false><<<gx, 256, 0, stream>>>(nullptr, Xhi, Xlo, w1h, w1l, b1, al1,
                                                  bl1, ar1, br1, ft, a1, a2, NN, 128);
    score_kernel<2><<<GE, 256, 0, stream>>>(esrc, edst, a1, a2, wbuf, EE);
    agg2_kernel<<<gn, 256, 0, stream>>>(ft, wbuf, off, esrc, Xhi, Xlo, NN);

    // ---- final layer: D=128, H=1 ----
    gemm_attn<64, false><<<gx, 256, 0, stream>>>(nullptr, Xhi, Xlo, wfh, wfl, bf, alf,
                                                 blf, arf, brf, ft, a1, a2, NN, 128);
    score_kernel<1><<<GE, 256, 0, stream>>>(esrc, edst, a1, a2, wbuf, EE);
    agg1_kernel<<<gn, 256, 0, stream>>>(ft, wbuf, off, esrc, (float*)d_out, NN);
}

// Round 7
// 380.590 us; speedup vs baseline: 1.1445x; 1.1445x over previous
//
#include <hip/hip_runtime.h>
#include <math.h>

#define NN 50000
#define EE 800000
#define DIN 256
#define NEG_SLOPE 0.01f

typedef __attribute__((ext_vector_type(8))) short bf16x8;
typedef __attribute__((ext_vector_type(8))) unsigned short u16x8;
typedef __attribute__((ext_vector_type(4))) float f32x4;

__device__ __forceinline__ unsigned short bf16_rne(float f) {
    unsigned int u = __float_as_uint(f);
    u += 0x7fffu + ((u >> 16) & 1u);
    return (unsigned short)(u >> 16);
}
__device__ __forceinline__ float bf16_tof(unsigned short h) {
    return __uint_as_float(((unsigned int)h) << 16);
}

// ---------------------------------------------------------------------------
// CSR build. histrank: count + per-edge rank (atomic off the scatter path).
// ---------------------------------------------------------------------------
__global__ __launch_bounds__(256) void histrank_kernel(const int* __restrict__ dst,
                                                       int* __restrict__ cnt,
                                                       int* __restrict__ pos, int E) {
    int e = blockIdx.x * 256 + threadIdx.x;
    if (e < E) pos[e] = atomicAdd(&cnt[dst[e]], 1);
}

__global__ __launch_bounds__(1024) void scanA_kernel(const int* __restrict__ cnt,
                                                     int* __restrict__ off,
                                                     int* __restrict__ aux, int Nn) {
    __shared__ int wsums[16];
    int tid = threadIdx.x, lane = tid & 63, w = tid >> 6;
    int i = blockIdx.x * 1024 + tid;
    int v = (i < Nn) ? cnt[i] : 0;
    int x = v;
#pragma unroll
    for (int d = 1; d < 64; d <<= 1) {
        int y = __shfl_up(x, d);
        if (lane >= d) x += y;
    }
    if (lane == 63) wsums[w] = x;
    __syncthreads();
    if (w == 0 && lane < 16) {
        int ws = wsums[lane];
#pragma unroll
        for (int d = 1; d < 16; d <<= 1) {
            int y = __shfl_up(ws, d);
            if (lane >= d) ws += y;
        }
        wsums[lane] = ws;
    }
    __syncthreads();
    int incl = x + (w > 0 ? wsums[w - 1] : 0);
    if (i < Nn) off[i + 1] = incl;
    if (tid == 1023) aux[blockIdx.x] = incl;
}

__global__ __launch_bounds__(1024) void scanC_kernel(const int* __restrict__ aux,
                                                     int* __restrict__ off, int Nn) {
    int b = blockIdx.x;
    int prefix = 0;
    for (int j = 0; j < b; j++) prefix += aux[j];
    int i = b * 1024 + threadIdx.x;
    if (i < Nn) off[i + 1] += prefix;
    if (i == 0 && b == 0) off[0] = 0;
}

__global__ __launch_bounds__(256) void scatter_kernel(const int* __restrict__ src,
                                                      const int* __restrict__ dst,
                                                      const int* __restrict__ off,
                                                      const int* __restrict__ pos,
                                                      int* __restrict__ esrc, int E) {
    int e = blockIdx.x * 256 + threadIdx.x;
    if (e >= E) return;
    int d = dst[e];
    esrc[off[d] + pos[e]] = src[e];
}

// ---------------------------------------------------------------------------
// One-shot weight convert + transpose: W[H][D][64] -> Wt hi/lo [H*64][D]
// ---------------------------------------------------------------------------
__global__ __launch_bounds__(256) void conv_w_kernel(
    const float* __restrict__ W0, const float* __restrict__ W1,
    const float* __restrict__ Wf, unsigned short* __restrict__ w0h,
    unsigned short* __restrict__ w0l, unsigned short* __restrict__ w1h,
    unsigned short* __restrict__ w1l, unsigned short* __restrict__ wfh,
    unsigned short* __restrict__ wfl) {
    int t = blockIdx.x * 256 + threadIdx.x;
    const float* W;
    unsigned short *oh, *ol;
    int D, u;
    if (t < 32768) { W = W0; oh = w0h; ol = w0l; D = 256; u = t; }
    else if (t < 49152) { W = W1; oh = w1h; ol = w1l; D = 128; u = t - 32768; }
    else if (t < 57344) { W = Wf; oh = wfh; ol = wfl; D = 128; u = t - 49152; }
    else return;
    int d = u & (D - 1);
    int n = u / D;
    float v = W[((size_t)(n >> 6) * D + d) * 64 + (n & 63)];
    unsigned short hi = bf16_rne(v);
    unsigned short lo = bf16_rne(v - bf16_tof(hi));
    oh[(size_t)n * D + d] = hi;
    ol[(size_t)n * D + d] = lo;
}

// ---------------------------------------------------------------------------
// MFMA bf16x3 GEMM + fused attention dots.
// ---------------------------------------------------------------------------
#define LDK 40

template <int NCOL, bool AFP32>
__global__ __launch_bounds__(256) void gemm_attn(
    const float* __restrict__ Xf, const unsigned short* __restrict__ Xhi,
    const unsigned short* __restrict__ Xlo, const unsigned short* __restrict__ Wthi,
    const unsigned short* __restrict__ Wtlo, const float* __restrict__ bias,
    const float* __restrict__ al, const float* __restrict__ bl,
    const float* __restrict__ ar, const float* __restrict__ br,
    float* __restrict__ FT, float* __restrict__ A1, float* __restrict__ A2,
    int Nn, int D) {
    const int H = NCOL / 64;
    const int NC16 = NCOL / 16;
    __shared__ __align__(16) unsigned short Ahi_s[64 * LDK];
    __shared__ __align__(16) unsigned short Alo_s[64 * LDK];
    __shared__ __align__(16) unsigned short Bhi_s[NCOL * LDK];
    __shared__ __align__(16) unsigned short Blo_s[NCOL * LDK];

    int tid = threadIdx.x;
    int wv = tid >> 6, l = tid & 63, lm = l & 15, quad = l >> 4;
    int m0 = blockIdx.x * 64;

    f32x4 acc[NC16];
#pragma unroll
    for (int c = 0; c < NC16; c++) acc[c] = (f32x4){0.f, 0.f, 0.f, 0.f};

    for (int d0 = 0; d0 < D; d0 += 32) {
        if (AFP32) {
#pragma unroll
            for (int i = 0; i < 2; i++) {
                int u = tid + i * 256;
                int row = u >> 3, c4 = u & 7;
                float4 v = make_float4(0.f, 0.f, 0.f, 0.f);
                if (m0 + row < Nn)
                    v = *(const float4*)&Xf[(size_t)(m0 + row) * D + d0 + c4 * 4];
                float f[4] = {v.x, v.y, v.z, v.w};
                unsigned short hi[4], lo[4];
#pragma unroll
                for (int j = 0; j < 4; j++) {
                    hi[j] = bf16_rne(f[j]);
                    lo[j] = bf16_rne(f[j] - bf16_tof(hi[j]));
                }
                *(ushort4*)&Ahi_s[row * LDK + c4 * 4] = make_ushort4(hi[0], hi[1], hi[2], hi[3]);
                *(ushort4*)&Alo_s[row * LDK + c4 * 4] = make_ushort4(lo[0], lo[1], lo[2], lo[3]);
            }
        } else {
            int row = tid >> 2, q = tid & 3;
            u16x8 vh = (u16x8)0, vl = (u16x8)0;
            if (m0 + row < Nn) {
                vh = *(const u16x8*)&Xhi[(size_t)(m0 + row) * D + d0 + q * 8];
                vl = *(const u16x8*)&Xlo[(size_t)(m0 + row) * D + d0 + q * 8];
            }
            *(u16x8*)&Ahi_s[row * LDK + q * 8] = vh;
            *(u16x8*)&Alo_s[row * LDK + q * 8] = vl;
        }
#pragma unroll
        for (int i = 0; i < NCOL / 64; i++) {
            int u = tid + i * 256;
            int n = u >> 2, q = u & 3;
            *(u16x8*)&Bhi_s[n * LDK + q * 8] =
                *(const u16x8*)&Wthi[(size_t)n * D + d0 + q * 8];
            *(u16x8*)&Blo_s[n * LDK + q * 8] =
                *(const u16x8*)&Wtlo[(size_t)n * D + d0 + q * 8];
        }
        __syncthreads();

        int arow = wv * 16 + lm;
        bf16x8 ah = *(const bf16x8*)&Ahi_s[arow * LDK + quad * 8];
        bf16x8 alo = *(const bf16x8*)&Alo_s[arow * LDK + quad * 8];
#pragma unroll
        for (int c = 0; c < NC16; c++) {
            bf16x8 bh = *(const bf16x8*)&Bhi_s[(c * 16 + lm) * LDK + quad * 8];
            bf16x8 blo = *(const bf16x8*)&Blo_s[(c * 16 + lm) * LDK + quad * 8];
            acc[c] = __builtin_amdgcn_mfma_f32_16x16x32_bf16(ah, bh, acc[c], 0, 0, 0);
            acc[c] = __builtin_amdgcn_mfma_f32_16x16x32_bf16(ah, blo, acc[c], 0, 0, 0);
            acc[c] = __builtin_amdgcn_mfma_f32_16x16x32_bf16(alo, bh, acc[c], 0, 0, 0);
        }
        __syncthreads();
    }

    float bj[NC16], alj[NC16], arj[NC16];
#pragma unroll
    for (int c = 0; c < NC16; c++) {
        bj[c] = bias[c * 16 + lm];
        alj[c] = al[c * 16 + lm];
        arj[c] = ar[c * 16 + lm];
    }
#pragma unroll
    for (int reg = 0; reg < 4; reg++) {
        int row = m0 + wv * 16 + quad * 4 + reg;
        bool ok = row < Nn;
        float s1[H], s2[H];
#pragma unroll
        for (int h = 0; h < H; h++) { s1[h] = 0.f; s2[h] = 0.f; }
#pragma unroll
        for (int c = 0; c < NC16; c++) {
            float o = acc[c][reg] + bj[c];
            int h = c >> 2;
            s1[h] += o * alj[c];
            s2[h] += o * arj[c];
            if (ok) FT[(size_t)row * NCOL + c * 16 + lm] = o;
        }
#pragma unroll
        for (int h = 0; h < H; h++) {
#pragma unroll
            for (int d = 1; d < 16; d <<= 1) {
                s1[h] += __shfl_xor(s1[h], d);
                s2[h] += __shfl_xor(s2[h], d);
            }
        }
        if (ok && lm == 0) {
#pragma unroll
            for (int h = 0; h < H; h++) {
                A1[(size_t)row * H + h] = s1[h] + bl[h];
                A2[(size_t)row * H + h] = s2[h] + br[h];
            }
        }
    }
}

// ---------------------------------------------------------------------------
// Edge aggregation + ELU, one wave per dst node. Inline scores (no max:
// scores are O(+-10), exp safe in fp32; alpha identical to reference).
// H=2: lane owns ft elems 2*lane, 2*lane+1; bf16 hi/lo output.
// ---------------------------------------------------------------------------
__global__ __launch_bounds__(256) void agg2_kernel(
    const float* __restrict__ ft, const float* __restrict__ a1,
    const float* __restrict__ a2, const int* __restrict__ off,
    const int* __restrict__ esrc, unsigned short* __restrict__ ohi,
    unsigned short* __restrict__ olo, int Nn) {
    __shared__ __align__(16) float ws[4][128];  // [wave][j*2 + h]
    __shared__ __align__(16) int sjs[4][64];
    int wv = threadIdx.x >> 6, lane = threadIdx.x & 63;
    int n = blockIdx.x * 4 + wv;
    if (n >= Nn) return;
    int o0 = off[n], deg = off[n + 1] - o0;
    int hs = lane >> 5, cl2 = lane * 2;
    if (deg == 0) {
        *(ushort2*)&ohi[(size_t)n * 128 + cl2] = make_ushort2(0, 0);
        *(ushort2*)&olo[(size_t)n * 128 + cl2] = make_ushort2(0, 0);
        return;
    }
    float2 a1v = *(const float2*)&a1[(size_t)n * 2];
    float ax = 0.f, ay = 0.f;
    float ds0 = 0.f, ds1 = 0.f;
    for (int e0 = 0; e0 < deg; e0 += 64) {
        int nE = min(64, deg - e0);
        float w0 = 0.f, w1 = 0.f;
        int sj = 0;
        if (lane < nE) {
            sj = esrc[o0 + e0 + lane];
            float2 a2j = *(const float2*)&a2[(size_t)sj * 2];
            float t0 = a1v.x + a2j.x;
            float t1 = a1v.y + a2j.y;
            t0 = t0 > 0.f ? t0 : NEG_SLOPE * t0;
            t1 = t1 > 0.f ? t1 : NEG_SLOPE * t1;
            w0 = __expf(t0);
            w1 = __expf(t1);
        }
        ds0 += w0;
        ds1 += w1;
        *(float2*)&ws[wv][lane * 2] = make_float2(w0, w1);
        sjs[wv][lane] = sj;
        // wave-synchronous: DS ops in a wave execute in order, no barrier.
        int j = 0;
        for (; j + 8 <= nE; j += 8) {
            float wb[8];
            int sb[8];
#pragma unroll
            for (int u = 0; u < 8; u++) {
                wb[u] = ws[wv][(j + u) * 2 + hs];
                sb[u] = sjs[wv][j + u];
            }
            float2 f[8];
#pragma unroll
            for (int u = 0; u < 8; u++)
                f[u] = *(const float2*)&ft[(size_t)sb[u] * 128 + cl2];
#pragma unroll
            for (int u = 0; u < 8; u++) {
                ax += wb[u] * f[u].x;
                ay += wb[u] * f[u].y;
            }
        }
        for (; j < nE; j++) {
            float w = ws[wv][j * 2 + hs];
            int s0 = sjs[wv][j];
            float2 f = *(const float2*)&ft[(size_t)s0 * 128 + cl2];
            ax += w * f.x;
            ay += w * f.y;
        }
    }
#pragma unroll
    for (int d = 1; d < 64; d <<= 1) {
        ds0 += __shfl_xor(ds0, d);
        ds1 += __shfl_xor(ds1, d);
    }
    float rd = 1.f / (hs ? ds1 : ds0);
    float rx = ax * rd, ry = ay * rd;
    rx = rx > 0.f ? rx : expm1f(rx);
    ry = ry > 0.f ? ry : expm1f(ry);
    unsigned short hx = bf16_rne(rx), hy = bf16_rne(ry);
    unsigned short lx = bf16_rne(rx - bf16_tof(hx)), ly = bf16_rne(ry - bf16_tof(hy));
    *(ushort2*)&ohi[(size_t)n * 128 + cl2] = make_ushort2(hx, hy);
    *(ushort2*)&olo[(size_t)n * 128 + cl2] = make_ushort2(lx, ly);
}

// H=1: lane owns ft elem `lane`; fp32 output (d_out).
__global__ __launch_bounds__(256) void agg1_kernel(
    const float* __restrict__ ft, const float* __restrict__ a1,
    const float* __restrict__ a2, const int* __restrict__ off,
    const int* __restrict__ esrc, float* __restrict__ out, int Nn) {
    __shared__ __align__(16) float ws[4][64];
    __shared__ __align__(16) int sjs[4][64];
    int wv = threadIdx.x >> 6, lane = threadIdx.x & 63;
    int n = blockIdx.x * 4 + wv;
    if (n >= Nn) return;
    int o0 = off[n], deg = off[n + 1] - o0;
    if (deg == 0) {
        out[(size_t)n * 64 + lane] = 0.f;
        return;
    }
    float a1v = a1[n];
    float acc = 0.f, dsum = 0.f;
    for (int e0 = 0; e0 < deg; e0 += 64) {
        int nE = min(64, deg - e0);
        float wl = 0.f;
        int sj = 0;
        if (lane < nE) {
            sj = esrc[o0 + e0 + lane];
            float t = a1v + a2[sj];
            t = t > 0.f ? t : NEG_SLOPE * t;
            wl = __expf(t);
        }
        dsum += wl;
        ws[wv][lane] = wl;
        sjs[wv][lane] = sj;
        int j = 0;
        for (; j + 8 <= nE; j += 8) {
            float wb[8];
            int sb[8];
#pragma unroll
            for (int u = 0; u < 8; u++) {
                wb[u] = ws[wv][j + u];
                sb[u] = sjs[wv][j + u];
            }
            float f[8];
#pragma unroll
            for (int u = 0; u < 8; u++) f[u] = ft[(size_t)sb[u] * 64 + lane];
#pragma unroll
            for (int u = 0; u < 8; u++) acc += wb[u] * f[u];
        }
        for (; j < nE; j++) acc += ws[wv][j] * ft[(size_t)sjs[wv][j] * 64 + lane];
    }
#pragma unroll
    for (int d = 1; d < 64; d <<= 1) dsum += __shfl_xor(dsum, d);
    float r = acc / dsum;
    out[(size_t)n * 64 + lane] = r > 0.f ? r : expm1f(r);
}

// ---------------------------------------------------------------------------
// launch
// ---------------------------------------------------------------------------
extern "C" void kernel_launch(void* const* d_in, const int* in_sizes, int n_in,
                              void* d_out, int out_size, void* d_ws, size_t ws_size,
                              hipStream_t stream) {
    const float* features = (const float*)d_in[0];
    const int* src = (const int*)d_in[1];
    const int* dst = (const int*)d_in[2];
    const float* W0 = (const float*)d_in[3];
    const float* b0 = (const float*)d_in[4];
    const float* al0 = (const float*)d_in[5];
    const float* bl0 = (const float*)d_in[6];
    const float* ar0 = (const float*)d_in[7];
    const float* br0 = (const float*)d_in[8];
    const float* W1 = (const float*)d_in[9];
    const float* b1 = (const float*)d_in[10];
    const float* al1 = (const float*)d_in[11];
    const float* bl1 = (const float*)d_in[12];
    const float* ar1 = (const float*)d_in[13];
    const float* br1 = (const float*)d_in[14];
    const float* Wf = (const float*)d_in[15];
    const float* bf = (const float*)d_in[16];
    const float* alf = (const float*)d_in[17];
    const float* blf = (const float*)d_in[18];
    const float* arf = (const float*)d_in[19];
    const float* brf = (const float*)d_in[20];

    char* p = (char*)d_ws;
    auto carve = [&](size_t bytes) {
        void* q = (void*)p;
        p += (bytes + 255) & ~(size_t)255;
        return q;
    };
    float* ft = (float*)carve((size_t)NN * 128 * 4);
    unsigned short* Xhi = (unsigned short*)carve((size_t)NN * 128 * 2);
    unsigned short* Xlo = (unsigned short*)carve((size_t)NN * 128 * 2);
    float* a1 = (float*)carve((size_t)NN * 2 * 4);
    float* a2 = (float*)carve((size_t)NN * 2 * 4);
    int* off = (int*)carve((size_t)(NN + 1) * 4);
    int* cnt = (int*)carve((size_t)NN * 4);
    int* esrc = (int*)carve((size_t)EE * 4);
    int* pos = (int*)carve((size_t)EE * 4);
    int* aux = (int*)carve(64 * 4);
    unsigned short* w0h = (unsigned short*)carve(32768 * 2);
    unsigned short* w0l = (unsigned short*)carve(32768 * 2);
    unsigned short* w1h = (unsigned short*)carve(16384 * 2);
    unsigned short* w1l = (unsigned short*)carve(16384 * 2);
    unsigned short* wfh = (unsigned short*)carve(8192 * 2);
    unsigned short* wfl = (unsigned short*)carve(8192 * 2);

    const int NB_SCAN = (NN + 1023) / 1024;
    const int GE = (EE + 255) / 256;

    // ---- CSR build + weight convert ----
    hipMemsetAsync(cnt, 0, (size_t)NN * 4, stream);
    histrank_kernel<<<GE, 256, 0, stream>>>(dst, cnt, pos, EE);
    scanA_kernel<<<NB_SCAN, 1024, 0, stream>>>(cnt, off, aux, NN);
    scanC_kernel<<<NB_SCAN, 1024, 0, stream>>>(aux, off, NN);
    scatter_kernel<<<GE, 256, 0, stream>>>(src, dst, off, pos, esrc, EE);
    conv_w_kernel<<<(57344 + 255) / 256, 256, 0, stream>>>(W0, W1, Wf, w0h, w0l, w1h,
                                                           w1l, wfh, wfl);

    const int gx = (NN + 63) / 64;
    const int gn = (NN + 3) / 4;

    // ---- layer 0: D=256, H=2 (fp32 A) ----
    gemm_attn<128, true><<<gx, 256, 0, stream>>>(features, nullptr, nullptr, w0h, w0l,
                                                 b0, al0, bl0, ar0, br0, ft, a1, a2,
                                                 NN, DIN);
    agg2_kernel<<<gn, 256, 0, stream>>>(ft, a1, a2, off, esrc, Xhi, Xlo, NN);

    // ---- layer 1: D=128, H=2 (bf16 A) ----
    gemm_attn<128, false><<<gx, 256, 0, stream>>>(nullptr, Xhi, Xlo, w1h, w1l, b1, al1,
                                                  bl1, ar1, br1, ft, a1, a2, NN, 128);
    agg2_kernel<<<gn, 256, 0, stream>>>(ft, a1, a2, off, esrc, Xhi, Xlo, NN);

    // ---- final layer: D=128, H=1 ----
    gemm_attn<64, false><<<gx, 256, 0, stream>>>(nullptr, Xhi, Xlo, wfh, wfl, bf, alf,
                                                 blf, arf, brf, ft, a1, a2, NN, 128);
    agg1_kernel<<<gn, 256, 0, stream>>>(ft, a1, a2, off, esrc, (float*)d_out, NN);
}

// Round 8
// 339.368 us; speedup vs baseline: 1.2835x; 1.1215x over previous
//
#include <hip/hip_runtime.h>
#include <math.h>

#define NN 50000
#define EE 800000
#define DIN 256
#define NEG_SLOPE 0.01f

typedef __attribute__((ext_vector_type(8))) short bf16x8;
typedef __attribute__((ext_vector_type(8))) unsigned short u16x8;
typedef __attribute__((ext_vector_type(4))) float f32x4;
typedef __attribute__((ext_vector_type(2))) _Float16 f16x2;

__device__ __forceinline__ unsigned short bf16_rne(float f) {
    unsigned int u = __float_as_uint(f);
    u += 0x7fffu + ((u >> 16) & 1u);
    return (unsigned short)(u >> 16);
}
__device__ __forceinline__ float bf16_tof(unsigned short h) {
    return __uint_as_float(((unsigned int)h) << 16);
}

// ---------------------------------------------------------------------------
// CSR build. histrank: count + per-edge rank (atomic off the scatter path).
// ---------------------------------------------------------------------------
__global__ __launch_bounds__(256) void histrank_kernel(const int* __restrict__ dst,
                                                       int* __restrict__ cnt,
                                                       int* __restrict__ pos, int E) {
    int e = blockIdx.x * 256 + threadIdx.x;
    if (e < E) pos[e] = atomicAdd(&cnt[dst[e]], 1);
}

__global__ __launch_bounds__(1024) void scanA_kernel(const int* __restrict__ cnt,
                                                     int* __restrict__ off,
                                                     int* __restrict__ aux, int Nn) {
    __shared__ int wsums[16];
    int tid = threadIdx.x, lane = tid & 63, w = tid >> 6;
    int i = blockIdx.x * 1024 + tid;
    int v = (i < Nn) ? cnt[i] : 0;
    int x = v;
#pragma unroll
    for (int d = 1; d < 64; d <<= 1) {
        int y = __shfl_up(x, d);
        if (lane >= d) x += y;
    }
    if (lane == 63) wsums[w] = x;
    __syncthreads();
    if (w == 0 && lane < 16) {
        int ws = wsums[lane];
#pragma unroll
        for (int d = 1; d < 16; d <<= 1) {
            int y = __shfl_up(ws, d);
            if (lane >= d) ws += y;
        }
        wsums[lane] = ws;
    }
    __syncthreads();
    int incl = x + (w > 0 ? wsums[w - 1] : 0);
    if (i < Nn) off[i + 1] = incl;
    if (tid == 1023) aux[blockIdx.x] = incl;
}

__global__ __launch_bounds__(1024) void scanC_kernel(const int* __restrict__ aux,
                                                     int* __restrict__ off, int Nn) {
    int b = blockIdx.x;
    int prefix = 0;
    for (int j = 0; j < b; j++) prefix += aux[j];
    int i = b * 1024 + threadIdx.x;
    if (i < Nn) off[i + 1] += prefix;
    if (i == 0 && b == 0) off[0] = 0;
}

__global__ __launch_bounds__(256) void scatter_kernel(const int* __restrict__ src,
                                                      const int* __restrict__ dst,
                                                      const int* __restrict__ off,
                                                      const int* __restrict__ pos,
                                                      int* __restrict__ esrc, int E) {
    int e = blockIdx.x * 256 + threadIdx.x;
    if (e >= E) return;
    int d = dst[e];
    esrc[off[d] + pos[e]] = src[e];
}

// ---------------------------------------------------------------------------
// One-shot weight convert + transpose: W[H][D][64] -> Wt hi/lo [H*64][D]
// ---------------------------------------------------------------------------
__global__ __launch_bounds__(256) void conv_w_kernel(
    const float* __restrict__ W0, const float* __restrict__ W1,
    const float* __restrict__ Wf, unsigned short* __restrict__ w0h,
    unsigned short* __restrict__ w0l, unsigned short* __restrict__ w1h,
    unsigned short* __restrict__ w1l, unsigned short* __restrict__ wfh,
    unsigned short* __restrict__ wfl) {
    int t = blockIdx.x * 256 + threadIdx.x;
    const float* W;
    unsigned short *oh, *ol;
    int D, u;
    if (t < 32768) { W = W0; oh = w0h; ol = w0l; D = 256; u = t; }
    else if (t < 49152) { W = W1; oh = w1h; ol = w1l; D = 128; u = t - 32768; }
    else if (t < 57344) { W = Wf; oh = wfh; ol = wfl; D = 128; u = t - 49152; }
    else return;
    int d = u & (D - 1);
    int n = u / D;
    float v = W[((size_t)(n >> 6) * D + d) * 64 + (n & 63)];
    unsigned short hi = bf16_rne(v);
    unsigned short lo = bf16_rne(v - bf16_tof(hi));
    oh[(size_t)n * D + d] = hi;
    ol[(size_t)n * D + d] = lo;
}

// ---------------------------------------------------------------------------
// MFMA bf16x3 GEMM + fused attention dots. FT written as fp16 (gather dtype).
// ---------------------------------------------------------------------------
#define LDK 40

template <int NCOL, bool AFP32>
__global__ __launch_bounds__(256) void gemm_attn(
    const float* __restrict__ Xf, const unsigned short* __restrict__ Xhi,
    const unsigned short* __restrict__ Xlo, const unsigned short* __restrict__ Wthi,
    const unsigned short* __restrict__ Wtlo, const float* __restrict__ bias,
    const float* __restrict__ al, const float* __restrict__ bl,
    const float* __restrict__ ar, const float* __restrict__ br,
    _Float16* __restrict__ FT, float* __restrict__ A1, float* __restrict__ A2,
    int Nn, int D) {
    const int H = NCOL / 64;
    const int NC16 = NCOL / 16;
    __shared__ __align__(16) unsigned short Ahi_s[64 * LDK];
    __shared__ __align__(16) unsigned short Alo_s[64 * LDK];
    __shared__ __align__(16) unsigned short Bhi_s[NCOL * LDK];
    __shared__ __align__(16) unsigned short Blo_s[NCOL * LDK];

    int tid = threadIdx.x;
    int wv = tid >> 6, l = tid & 63, lm = l & 15, quad = l >> 4;
    int m0 = blockIdx.x * 64;

    f32x4 acc[NC16];
#pragma unroll
    for (int c = 0; c < NC16; c++) acc[c] = (f32x4){0.f, 0.f, 0.f, 0.f};

    for (int d0 = 0; d0 < D; d0 += 32) {
        if (AFP32) {
#pragma unroll
            for (int i = 0; i < 2; i++) {
                int u = tid + i * 256;
                int row = u >> 3, c4 = u & 7;
                float4 v = make_float4(0.f, 0.f, 0.f, 0.f);
                if (m0 + row < Nn)
                    v = *(const float4*)&Xf[(size_t)(m0 + row) * D + d0 + c4 * 4];
                float f[4] = {v.x, v.y, v.z, v.w};
                unsigned short hi[4], lo[4];
#pragma unroll
                for (int j = 0; j < 4; j++) {
                    hi[j] = bf16_rne(f[j]);
                    lo[j] = bf16_rne(f[j] - bf16_tof(hi[j]));
                }
                *(ushort4*)&Ahi_s[row * LDK + c4 * 4] = make_ushort4(hi[0], hi[1], hi[2], hi[3]);
                *(ushort4*)&Alo_s[row * LDK + c4 * 4] = make_ushort4(lo[0], lo[1], lo[2], lo[3]);
            }
        } else {
            int row = tid >> 2, q = tid & 3;
            u16x8 vh = (u16x8)0, vl = (u16x8)0;
            if (m0 + row < Nn) {
                vh = *(const u16x8*)&Xhi[(size_t)(m0 + row) * D + d0 + q * 8];
                vl = *(const u16x8*)&Xlo[(size_t)(m0 + row) * D + d0 + q * 8];
            }
            *(u16x8*)&Ahi_s[row * LDK + q * 8] = vh;
            *(u16x8*)&Alo_s[row * LDK + q * 8] = vl;
        }
#pragma unroll
        for (int i = 0; i < NCOL / 64; i++) {
            int u = tid + i * 256;
            int n = u >> 2, q = u & 3;
            *(u16x8*)&Bhi_s[n * LDK + q * 8] =
                *(const u16x8*)&Wthi[(size_t)n * D + d0 + q * 8];
            *(u16x8*)&Blo_s[n * LDK + q * 8] =
                *(const u16x8*)&Wtlo[(size_t)n * D + d0 + q * 8];
        }
        __syncthreads();

        int arow = wv * 16 + lm;
        bf16x8 ah = *(const bf16x8*)&Ahi_s[arow * LDK + quad * 8];
        bf16x8 alo = *(const bf16x8*)&Alo_s[arow * LDK + quad * 8];
#pragma unroll
        for (int c = 0; c < NC16; c++) {
            bf16x8 bh = *(const bf16x8*)&Bhi_s[(c * 16 + lm) * LDK + quad * 8];
            bf16x8 blo = *(const bf16x8*)&Blo_s[(c * 16 + lm) * LDK + quad * 8];
            acc[c] = __builtin_amdgcn_mfma_f32_16x16x32_bf16(ah, bh, acc[c], 0, 0, 0);
            acc[c] = __builtin_amdgcn_mfma_f32_16x16x32_bf16(ah, blo, acc[c], 0, 0, 0);
            acc[c] = __builtin_amdgcn_mfma_f32_16x16x32_bf16(alo, bh, acc[c], 0, 0, 0);
        }
        __syncthreads();
    }

    float bj[NC16], alj[NC16], arj[NC16];
#pragma unroll
    for (int c = 0; c < NC16; c++) {
        bj[c] = bias[c * 16 + lm];
        alj[c] = al[c * 16 + lm];
        arj[c] = ar[c * 16 + lm];
    }
#pragma unroll
    for (int reg = 0; reg < 4; reg++) {
        int row = m0 + wv * 16 + quad * 4 + reg;
        bool ok = row < Nn;
        float s1[H], s2[H];
#pragma unroll
        for (int h = 0; h < H; h++) { s1[h] = 0.f; s2[h] = 0.f; }
#pragma unroll
        for (int c = 0; c < NC16; c++) {
            float o = acc[c][reg] + bj[c];
            int h = c >> 2;
            s1[h] += o * alj[c];
            s2[h] += o * arj[c];
            if (ok) FT[(size_t)row * NCOL + c * 16 + lm] = (_Float16)o;
        }
#pragma unroll
        for (int h = 0; h < H; h++) {
#pragma unroll
            for (int d = 1; d < 16; d <<= 1) {
                s1[h] += __shfl_xor(s1[h], d);
                s2[h] += __shfl_xor(s2[h], d);
            }
        }
        if (ok && lm == 0) {
#pragma unroll
            for (int h = 0; h < H; h++) {
                A1[(size_t)row * H + h] = s1[h] + bl[h];
                A2[(size_t)row * H + h] = s2[h] + br[h];
            }
        }
    }
}

// ---------------------------------------------------------------------------
// Edge aggregation + ELU, one wave per dst node. Inline scores (no max:
// scores are O(+-10), exp safe in fp32; alpha identical to reference).
// ft gathered as fp16 (half the bytes of fp32 — the agg is BW-bound).
// H=2: lane owns ft elems 2*lane, 2*lane+1; bf16 hi/lo output for next GEMM.
// ---------------------------------------------------------------------------
__global__ __launch_bounds__(256) void agg2_kernel(
    const _Float16* __restrict__ ft, const float* __restrict__ a1,
    const float* __restrict__ a2, const int* __restrict__ off,
    const int* __restrict__ esrc, unsigned short* __restrict__ ohi,
    unsigned short* __restrict__ olo, int Nn) {
    __shared__ __align__(16) float ws[4][128];  // [wave][j*2 + h]
    __shared__ __align__(16) int sjs[4][64];
    int wv = threadIdx.x >> 6, lane = threadIdx.x & 63;
    int n = blockIdx.x * 4 + wv;
    if (n >= Nn) return;
    int o0 = off[n], deg = off[n + 1] - o0;
    int hs = lane >> 5, cl2 = lane * 2;
    if (deg == 0) {
        *(ushort2*)&ohi[(size_t)n * 128 + cl2] = make_ushort2(0, 0);
        *(ushort2*)&olo[(size_t)n * 128 + cl2] = make_ushort2(0, 0);
        return;
    }
    float2 a1v = *(const float2*)&a1[(size_t)n * 2];
    float ax = 0.f, ay = 0.f;
    float ds0 = 0.f, ds1 = 0.f;
    for (int e0 = 0; e0 < deg; e0 += 64) {
        int nE = min(64, deg - e0);
        float w0 = 0.f, w1 = 0.f;
        int sj = 0;
        if (lane < nE) {
            sj = esrc[o0 + e0 + lane];
            float2 a2j = *(const float2*)&a2[(size_t)sj * 2];
            float t0 = a1v.x + a2j.x;
            float t1 = a1v.y + a2j.y;
            t0 = t0 > 0.f ? t0 : NEG_SLOPE * t0;
            t1 = t1 > 0.f ? t1 : NEG_SLOPE * t1;
            w0 = __expf(t0);
            w1 = __expf(t1);
        }
        ds0 += w0;
        ds1 += w1;
        *(float2*)&ws[wv][lane * 2] = make_float2(w0, w1);
        sjs[wv][lane] = sj;
        // wave-synchronous: DS ops in a wave execute in order, no barrier.
        int j = 0;
        for (; j + 8 <= nE; j += 8) {
            float wb[8];
            int sb[8];
#pragma unroll
            for (int u = 0; u < 8; u++) {
                wb[u] = ws[wv][(j + u) * 2 + hs];
                sb[u] = sjs[wv][j + u];
            }
            f16x2 f[8];
#pragma unroll
            for (int u = 0; u < 8; u++)
                f[u] = *(const f16x2*)&ft[(size_t)sb[u] * 128 + cl2];
#pragma unroll
            for (int u = 0; u < 8; u++) {
                ax += wb[u] * (float)f[u].x;
                ay += wb[u] * (float)f[u].y;
            }
        }
        for (; j < nE; j++) {
            float w = ws[wv][j * 2 + hs];
            int s0 = sjs[wv][j];
            f16x2 f = *(const f16x2*)&ft[(size_t)s0 * 128 + cl2];
            ax += w * (float)f.x;
            ay += w * (float)f.y;
        }
    }
#pragma unroll
    for (int d = 1; d < 64; d <<= 1) {
        ds0 += __shfl_xor(ds0, d);
        ds1 += __shfl_xor(ds1, d);
    }
    float rd = 1.f / (hs ? ds1 : ds0);
    float rx = ax * rd, ry = ay * rd;
    rx = rx > 0.f ? rx : expm1f(rx);
    ry = ry > 0.f ? ry : expm1f(ry);
    unsigned short hx = bf16_rne(rx), hy = bf16_rne(ry);
    unsigned short lx = bf16_rne(rx - bf16_tof(hx)), ly = bf16_rne(ry - bf16_tof(hy));
    *(ushort2*)&ohi[(size_t)n * 128 + cl2] = make_ushort2(hx, hy);
    *(ushort2*)&olo[(size_t)n * 128 + cl2] = make_ushort2(lx, ly);
}

// H=1: lane owns ft elem `lane` (fp16 gather); fp32 output (d_out).
__global__ __launch_bounds__(256) void agg1_kernel(
    const _Float16* __restrict__ ft, const float* __restrict__ a1,
    const float* __restrict__ a2, const int* __restrict__ off,
    const int* __restrict__ esrc, float* __restrict__ out, int Nn) {
    __shared__ __align__(16) float ws[4][64];
    __shared__ __align__(16) int sjs[4][64];
    int wv = threadIdx.x >> 6, lane = threadIdx.x & 63;
    int n = blockIdx.x * 4 + wv;
    if (n >= Nn) return;
    int o0 = off[n], deg = off[n + 1] - o0;
    if (deg == 0) {
        out[(size_t)n * 64 + lane] = 0.f;
        return;
    }
    float a1v = a1[n];
    float acc = 0.f, dsum = 0.f;
    for (int e0 = 0; e0 < deg; e0 += 64) {
        int nE = min(64, deg - e0);
        float wl = 0.f;
        int sj = 0;
        if (lane < nE) {
            sj = esrc[o0 + e0 + lane];
            float t = a1v + a2[sj];
            t = t > 0.f ? t : NEG_SLOPE * t;
            wl = __expf(t);
        }
        dsum += wl;
        ws[wv][lane] = wl;
        sjs[wv][lane] = sj;
        int j = 0;
        for (; j + 8 <= nE; j += 8) {
            float wb[8];
            int sb[8];
#pragma unroll
            for (int u = 0; u < 8; u++) {
                wb[u] = ws[wv][j + u];
                sb[u] = sjs[wv][j + u];
            }
            _Float16 f[8];
#pragma unroll
            for (int u = 0; u < 8; u++) f[u] = ft[(size_t)sb[u] * 64 + lane];
#pragma unroll
            for (int u = 0; u < 8; u++) acc += wb[u] * (float)f[u];
        }
        for (; j < nE; j++)
            acc += ws[wv][j] * (float)ft[(size_t)sjs[wv][j] * 64 + lane];
    }
#pragma unroll
    for (int d = 1; d < 64; d <<= 1) dsum += __shfl_xor(dsum, d);
    float r = acc / dsum;
    out[(size_t)n * 64 + lane] = r > 0.f ? r : expm1f(r);
}

// ---------------------------------------------------------------------------
// launch
// ---------------------------------------------------------------------------
extern "C" void kernel_launch(void* const* d_in, const int* in_sizes, int n_in,
                              void* d_out, int out_size, void* d_ws, size_t ws_size,
                              hipStream_t stream) {
    const float* features = (const float*)d_in[0];
    const int* src = (const int*)d_in[1];
    const int* dst = (const int*)d_in[2];
    const float* W0 = (const float*)d_in[3];
    const float* b0 = (const float*)d_in[4];
    const float* al0 = (const float*)d_in[5];
    const float* bl0 = (const float*)d_in[6];
    const float* ar0 = (const float*)d_in[7];
    const float* br0 = (const float*)d_in[8];
    const float* W1 = (const float*)d_in[9];
    const float* b1 = (const float*)d_in[10];
    const float* al1 = (const float*)d_in[11];
    const float* bl1 = (const float*)d_in[12];
    const float* ar1 = (const float*)d_in[13];
    const float* br1 = (const float*)d_in[14];
    const float* Wf = (const float*)d_in[15];
    const float* bf = (const float*)d_in[16];
    const float* alf = (const float*)d_in[17];
    const float* blf = (const float*)d_in[18];
    const float* arf = (const float*)d_in[19];
    const float* brf = (const float*)d_in[20];

    char* p = (char*)d_ws;
    auto carve = [&](size_t bytes) {
        void* q = (void*)p;
        p += (bytes + 255) & ~(size_t)255;
        return q;
    };
    _Float16* ft = (_Float16*)carve((size_t)NN * 128 * 2);
    unsigned short* Xhi = (unsigned short*)carve((size_t)NN * 128 * 2);
    unsigned short* Xlo = (unsigned short*)carve((size_t)NN * 128 * 2);
    float* a1 = (float*)carve((size_t)NN * 2 * 4);
    float* a2 = (float*)carve((size_t)NN * 2 * 4);
    int* off = (int*)carve((size_t)(NN + 1) * 4);
    int* cnt = (int*)carve((size_t)NN * 4);
    int* esrc = (int*)carve((size_t)EE * 4);
    int* pos = (int*)carve((size_t)EE * 4);
    int* aux = (int*)carve(64 * 4);
    unsigned short* w0h = (unsigned short*)carve(32768 * 2);
    unsigned short* w0l = (unsigned short*)carve(32768 * 2);
    unsigned short* w1h = (unsigned short*)carve(16384 * 2);
    unsigned short* w1l = (unsigned short*)carve(16384 * 2);
    unsigned short* wfh = (unsigned short*)carve(8192 * 2);
    unsigned short* wfl = (unsigned short*)carve(8192 * 2);

    const int NB_SCAN = (NN + 1023) / 1024;
    const int GE = (EE + 255) / 256;

    // ---- CSR build + weight convert ----
    hipMemsetAsync(cnt, 0, (size_t)NN * 4, stream);
    histrank_kernel<<<GE, 256, 0, stream>>>(dst, cnt, pos, EE);
    scanA_kernel<<<NB_SCAN, 1024, 0, stream>>>(cnt, off, aux, NN);
    scanC_kernel<<<NB_SCAN, 1024, 0, stream>>>(aux, off, NN);
    scatter_kernel<<<GE, 256, 0, stream>>>(src, dst, off, pos, esrc, EE);
    conv_w_kernel<<<(57344 + 255) / 256, 256, 0, stream>>>(W0, W1, Wf, w0h, w0l, w1h,
                                                           w1l, wfh, wfl);

    const int gx = (NN + 63) / 64;
    const int gn = (NN + 3) / 4;

    // ---- layer 0: D=256, H=2 (fp32 A) ----
    gemm_attn<128, true><<<gx, 256, 0, stream>>>(features, nullptr, nullptr, w0h, w0l,
                                                 b0, al0, bl0, ar0, br0, ft, a1, a2,
                                                 NN, DIN);
    agg2_kernel<<<gn, 256, 0, stream>>>(ft, a1, a2, off, esrc, Xhi, Xlo, NN);

    // ---- layer 1: D=128, H=2 (bf16 A) ----
    gemm_attn<128, false><<<gx, 256, 0, stream>>>(nullptr, Xhi, Xlo, w1h, w1l, b1, al1,
                                                  bl1, ar1, br1, ft, a1, a2, NN, 128);
    agg2_kernel<<<gn, 256, 0, stream>>>(ft, a1, a2, off, esrc, Xhi, Xlo, NN);

    // ---- final layer: D=128, H=1 ----
    gemm_attn<64, false><<<gx, 256, 0, stream>>>(nullptr, Xhi, Xlo, wfh, wfl, bf, alf,
                                                 blf, arf, brf, ft, a1, a2, NN, 128);
    agg1_kernel<<<gn, 256, 0, stream>>>(ft, a1, a2, off, esrc, (float*)d_out, NN);
}